// Round 1
// 1223.436 us; speedup vs baseline: 1.4953x; 1.4953x over previous
//
#include <hip/hip_runtime.h>

typedef unsigned short u16;
typedef unsigned int u32;
typedef __bf16 bf16;
typedef bf16 bf16x8 __attribute__((ext_vector_type(8)));
typedef float f32x4 __attribute__((ext_vector_type(4)));

#define CIN 384
#define C3 1152
#define NPIX 16384
#define NB 8
#define DH 48
#define IMG 128
#define LDK 40  // BK=32 + 8 pad: frag reads land 2-way (free) on 32 banks

__device__ __forceinline__ u16 f2bf(float f) {
  u32 u = __float_as_uint(f);
  u32 r = (u + 0x7fffu + ((u >> 16) & 1u)) >> 16;  // RNE
  return (u16)r;
}
__device__ __forceinline__ float bf2f(u16 a) { return __uint_as_float(((u32)a) << 16); }
__device__ __forceinline__ u32 pk(u16 a, u16 b) { return (u32)a | ((u32)b << 16); }

// ---------------- K0: LayerNorm stats (mu, rstd per pixel) ----------------
__global__ __launch_bounds__(256) void k_stats(const float* __restrict__ x,
                                               float* __restrict__ mu,
                                               float* __restrict__ rstd) {
  int idx = blockIdx.x * 256 + threadIdx.x;   // B*N = 131072
  int b = idx >> 14, p = idx & (NPIX - 1);
  const float* xp = x + (size_t)b * CIN * NPIX + p;
  float s = 0.f, s2 = 0.f;
#pragma unroll 4
  for (int c = 0; c < CIN; ++c) {
    float v = xp[(size_t)c * NPIX];
    s += v; s2 += v * v;
  }
  float m = s * (1.f / CIN);
  float var = s2 * (1.f / CIN) - m * m;
  mu[idx] = m;
  rstd[idx] = rsqrtf(var + 1e-5f);
}

// ---------------- K1: pointwise conv GEMM with fused LN ----------------
// qkv_pre[b][o][p] = sum_c W[o][c] * xn[b][c][p],  o in [0,1152)
__global__ __launch_bounds__(256) void k_pconv(const float* __restrict__ x,
                                               const float* __restrict__ wp,
                                               const float* __restrict__ lnw,
                                               const float* __restrict__ mu,
                                               const float* __restrict__ rstd,
                                               u16* __restrict__ qkv_pre) {
  __shared__ u16 As[128 * LDK];  // W tile  [o][k], k-contig
  __shared__ u16 Bs[128 * LDK];  // xn tile [p][k], k-contig (transposed on store)
  int blk = blockIdx.x;
  int pt = blk & 127;
  int ot = (blk >> 7) % 9;
  int b = blk / (9 * 128);
  int o0 = ot * 128, p0 = pt * 128;
  int tid = threadIdx.x;
  int lane = tid & 63, wave = tid >> 6;
  int ml = lane & 15, quad = lane >> 4;
  int wm = (wave & 1) * 64, wn = (wave >> 1) * 64;
  int a_row = tid >> 1, a_cs = (tid & 1) * 16;
  int b_p = tid & 127, b_cs = (tid >> 7) * 16;

  const float* xb = x + (size_t)b * CIN * NPIX + p0 + b_p;
  float mu_v = mu[b * NPIX + p0 + b_p];
  float rs_v = rstd[b * NPIX + p0 + b_p];

  f32x4 acc[4][4];
#pragma unroll
  for (int i = 0; i < 4; ++i)
#pragma unroll
    for (int j = 0; j < 4; ++j) acc[i][j] = (f32x4){0.f, 0.f, 0.f, 0.f};

  for (int kc = 0; kc < CIN; kc += 32) {
    {  // A tile: 16 contiguous floats per thread
      const float* ap = wp + (size_t)(o0 + a_row) * CIN + kc + a_cs;
      u16 t[16];
#pragma unroll
      for (int i = 0; i < 16; ++i) t[i] = f2bf(ap[i]);
      uint4 v0 = make_uint4(pk(t[0], t[1]), pk(t[2], t[3]), pk(t[4], t[5]), pk(t[6], t[7]));
      uint4 v1 = make_uint4(pk(t[8], t[9]), pk(t[10], t[11]), pk(t[12], t[13]), pk(t[14], t[15]));
      *(uint4*)&As[a_row * LDK + a_cs] = v0;
      *(uint4*)&As[a_row * LDK + a_cs + 8] = v1;
    }
    {  // B tile: coalesced along p, LN applied, stored transposed [p][k]
      u16 t[16];
#pragma unroll
      for (int i = 0; i < 16; ++i) {
        int c = kc + b_cs + i;
        float xv = xb[(size_t)c * NPIX];
        t[i] = f2bf((xv - mu_v) * rs_v * lnw[c]);
      }
      uint4 v0 = make_uint4(pk(t[0], t[1]), pk(t[2], t[3]), pk(t[4], t[5]), pk(t[6], t[7]));
      uint4 v1 = make_uint4(pk(t[8], t[9]), pk(t[10], t[11]), pk(t[12], t[13]), pk(t[14], t[15]));
      *(uint4*)&Bs[b_p * LDK + b_cs] = v0;
      *(uint4*)&Bs[b_p * LDK + b_cs + 8] = v1;
    }
    __syncthreads();
    bf16x8 af[4], bfr[4];
#pragma unroll
    for (int mt = 0; mt < 4; ++mt)
      af[mt] = *(const bf16x8*)&As[(wm + mt * 16 + ml) * LDK + quad * 8];
#pragma unroll
    for (int nt = 0; nt < 4; ++nt)
      bfr[nt] = *(const bf16x8*)&Bs[(wn + nt * 16 + ml) * LDK + quad * 8];
#pragma unroll
    for (int mt = 0; mt < 4; ++mt)
#pragma unroll
      for (int nt = 0; nt < 4; ++nt)
        acc[mt][nt] = __builtin_amdgcn_mfma_f32_16x16x32_bf16(af[mt], bfr[nt], acc[mt][nt], 0, 0, 0);
    __syncthreads();
  }
#pragma unroll
  for (int mt = 0; mt < 4; ++mt)
#pragma unroll
    for (int nt = 0; nt < 4; ++nt) {
      int o = o0 + wm + mt * 16 + quad * 4;
      int p = p0 + wn + nt * 16 + ml;
      size_t base = ((size_t)(b * C3 + o)) * NPIX + p;
#pragma unroll
      for (int r = 0; r < 4; ++r)
        qkv_pre[base + (size_t)r * NPIX] = f2bf(acc[mt][nt][r]);
    }
}

// ---------------- K2: depthwise 3x3, zero pad — vectorized, 8 px/thread ----------------
// Each thread computes 8 consecutive x-pixels of one (channel,row).
// Per tap-row: one aligned uint4 load (8 bf16) + two boundary u16 loads.
// Block = 256 threads = 2048 px = 16 image rows of one channel -> channel is
// block-uniform, so the 9 weights are uniform (scalar-cache) loads.
__global__ __launch_bounds__(256) void k_dconv(const u16* __restrict__ pre,
                                               const float* __restrict__ wd,
                                               u16* __restrict__ post) {
  int bidx = blockIdx.x;
  int cg = bidx >> 3;              // b*C3 + ch   (8 blocks per channel-image)
  int ch = cg % C3;
  int tid = threadIdx.x;
  int y = (bidx & 7) * 16 + (tid >> 4);
  int x0 = (tid & 15) * 8;
  const u16* pb = pre + (size_t)cg * NPIX;
  const float* wc = wd + ch * 9;
  float w[9];
#pragma unroll
  for (int i = 0; i < 9; ++i) w[i] = wc[i];

  float a[8];
#pragma unroll
  for (int i = 0; i < 8; ++i) a[i] = 0.f;

#pragma unroll
  for (int ky = 0; ky < 3; ++ky) {
    int yy = y + ky - 1;
    if (yy >= 0 && yy < IMG) {
      const u16* row = pb + yy * IMG + x0;
      uint4 v = *(const uint4*)row;          // 8 bf16, 16B aligned, coalesced
      const u16* pv = (const u16*)&v;
      float r[10];
#pragma unroll
      for (int i = 0; i < 8; ++i) r[i + 1] = bf2f(pv[i]);
      r[0] = (x0 > 0) ? bf2f(row[-1]) : 0.f;
      r[9] = (x0 < IMG - 8) ? bf2f(row[8]) : 0.f;
#pragma unroll
      for (int kx = 0; kx < 3; ++kx) {
        float wv = w[ky * 3 + kx];
#pragma unroll
        for (int i = 0; i < 8; ++i) a[i] += r[i + kx] * wv;
      }
    }
  }
  u16 o[8];
#pragma unroll
  for (int i = 0; i < 8; ++i) o[i] = f2bf(a[i]);
  uint4 ov = make_uint4(pk(o[0], o[1]), pk(o[2], o[3]), pk(o[4], o[5]), pk(o[6], o[7]));
  *(uint4*)(post + (size_t)cg * NPIX + y * IMG + x0) = ov;
}

// ---------------- K3: Q^T K split-K partials ----------------
// score[i][j] = sum_n q[i][n] k[j][n]; 64 chunks of 256 pixels, 1 wave each
__global__ __launch_bounds__(64) void k_score(const u16* __restrict__ post,
                                              float* __restrict__ partial) {
  int blk = blockIdx.x;  // bh*64 + chunk
  int chunk = blk & 63, bh = blk >> 6;
  int b = bh >> 3, h = bh & 7;
  int lane = threadIdx.x;
  int ml = lane & 15, quad = lane >> 4;
  int n0 = chunk * 256;
  const u16* qp[3];
  const u16* kp[3];
#pragma unroll
  for (int t = 0; t < 3; ++t) {
    qp[t] = post + ((size_t)(b * C3 + h * DH + t * 16 + ml)) * NPIX + n0 + quad * 8;
    kp[t] = post + ((size_t)(b * C3 + CIN + h * DH + t * 16 + ml)) * NPIX + n0 + quad * 8;
  }
  f32x4 acc[3][3];
#pragma unroll
  for (int i = 0; i < 3; ++i)
#pragma unroll
    for (int j = 0; j < 3; ++j) acc[i][j] = (f32x4){0.f, 0.f, 0.f, 0.f};
  for (int ks = 0; ks < 256; ks += 32) {
    bf16x8 qf[3], kf[3];
#pragma unroll
    for (int t = 0; t < 3; ++t) {
      qf[t] = *(const bf16x8*)(qp[t] + ks);
      kf[t] = *(const bf16x8*)(kp[t] + ks);
    }
#pragma unroll
    for (int it = 0; it < 3; ++it)
#pragma unroll
      for (int jt = 0; jt < 3; ++jt)
        acc[it][jt] = __builtin_amdgcn_mfma_f32_16x16x32_bf16(qf[it], kf[jt], acc[it][jt], 0, 0, 0);
  }
  float* pp = partial + (size_t)blk * (DH * DH);
#pragma unroll
  for (int it = 0; it < 3; ++it)
#pragma unroll
    for (int jt = 0; jt < 3; ++jt)
#pragma unroll
      for (int r = 0; r < 4; ++r)
        pp[(it * 16 + quad * 4 + r) * DH + jt * 16 + ml] = acc[it][jt][r];
}

// ---------------- K4: reduce partials, softmax, emit score^T (K-padded) ----------------
__global__ __launch_bounds__(256) void k_softmax(const float* __restrict__ partial,
                                                 const float* __restrict__ alpha,
                                                 u16* __restrict__ scoreT) {
  __shared__ float sc[DH * DH];
  __shared__ float pr[DH * DH];
  int bh = blockIdx.x, tid = threadIdx.x;
  const float* pp = partial + (size_t)bh * 64 * (DH * DH);
  for (int e = tid; e < DH * DH; e += 256) {
    float s = 0.f;
    for (int c = 0; c < 64; ++c) s += pp[(size_t)c * (DH * DH) + e];
    sc[e] = s;
  }
  __syncthreads();
  float inv_a = 1.0f / alpha[0];
  if (tid < DH) {
    int i = tid;
    float mx = -1e30f;
    for (int j = 0; j < DH; ++j) mx = fmaxf(mx, sc[i * DH + j] * inv_a);
    float sum = 0.f;
    for (int j = 0; j < DH; ++j) {
      float e = __expf(sc[i * DH + j] * inv_a - mx);
      pr[i * DH + j] = e;
      sum += e;
    }
    float r = 1.f / sum;
    for (int j = 0; j < DH; ++j) pr[i * DH + j] *= r;
  }
  __syncthreads();
  u16* st = scoreT + (size_t)bh * DH * 64;
  for (int e = tid; e < DH * 64; e += 256) {
    int j = e >> 6, i = e & 63;
    st[e] = f2bf(i < DH ? pr[i * DH + j] : 0.f);  // zero-pad K to 64
  }
}

// ---------------- K5: attn^T[j][n] = sum_i score^T[j][i] * v[i][n] ----------------
#define VS_LD 72
__global__ __launch_bounds__(256) void k_attnv(const u16* __restrict__ post,
                                               const u16* __restrict__ scoreT,
                                               u16* __restrict__ attn) {
  __shared__ u16 Vs[128 * VS_LD];  // V^T tile: [n][i], i-contig
  int blk = blockIdx.x;
  int pt = blk & 127, h = (blk >> 7) & 7, b = blk >> 10;
  int p0 = pt * 128;
  int tid = threadIdx.x, lane = tid & 63, wave = tid >> 6;
  int ml = lane & 15, quad = lane >> 4;
  {  // stage V transposed: thread owns one n, 32 i's -> 4x b128 LDS writes
    int n = tid & 127;
    int i0 = (tid >> 7) * 32;
    size_t vbase = ((size_t)(b * C3 + 2 * CIN + h * DH)) * NPIX + p0 + n;
    u16 t[32];
#pragma unroll
    for (int i = 0; i < 32; ++i) t[i] = post[vbase + (size_t)(i0 + i) * NPIX];
#pragma unroll
    for (int q2 = 0; q2 < 4; ++q2) {
      uint4 v = make_uint4(pk(t[q2 * 8 + 0], t[q2 * 8 + 1]), pk(t[q2 * 8 + 2], t[q2 * 8 + 3]),
                           pk(t[q2 * 8 + 4], t[q2 * 8 + 5]), pk(t[q2 * 8 + 6], t[q2 * 8 + 7]));
      *(uint4*)&Vs[n * VS_LD + i0 + q2 * 8] = v;
    }
  }
  __syncthreads();
  const u16* sT = scoreT + (size_t)(b * 8 + h) * (DH * 64);
  int wn = wave * 32;
  f32x4 acc[3][2];
#pragma unroll
  for (int i = 0; i < 3; ++i)
#pragma unroll
    for (int j = 0; j < 2; ++j) acc[i][j] = (f32x4){0.f, 0.f, 0.f, 0.f};
#pragma unroll
  for (int ks = 0; ks < 2; ++ks) {
    bf16x8 a3[3], b2[2];
#pragma unroll
    for (int mt = 0; mt < 3; ++mt)
      a3[mt] = *(const bf16x8*)&sT[(mt * 16 + ml) * 64 + ks * 32 + quad * 8];
#pragma unroll
    for (int nt = 0; nt < 2; ++nt)
      b2[nt] = *(const bf16x8*)&Vs[(wn + nt * 16 + ml) * VS_LD + ks * 32 + quad * 8];
#pragma unroll
    for (int mt = 0; mt < 3; ++mt)
#pragma unroll
      for (int nt = 0; nt < 2; ++nt)
        acc[mt][nt] = __builtin_amdgcn_mfma_f32_16x16x32_bf16(a3[mt], b2[nt], acc[mt][nt], 0, 0, 0);
  }
#pragma unroll
  for (int mt = 0; mt < 3; ++mt)
#pragma unroll
    for (int nt = 0; nt < 2; ++nt)
#pragma unroll
      for (int r = 0; r < 4; ++r) {
        int j = mt * 16 + quad * 4 + r;
        int n = wn + nt * 16 + ml;
        attn[((size_t)(b * CIN + h * DH + j)) * NPIX + p0 + n] = f2bf(acc[mt][nt][r]);
      }
}

// ---------------- K6: output GEMM + residual ----------------
__global__ __launch_bounds__(256) void k_out(const u16* __restrict__ attn,
                                             const float* __restrict__ wo,
                                             const float* __restrict__ x,
                                             float* __restrict__ out) {
  __shared__ u16 As[128 * LDK];
  __shared__ u16 Bs[128 * LDK];
  int blk = blockIdx.x;
  int pt = blk & 127;
  int ot = (blk >> 7) % 3;
  int b = blk / (3 * 128);
  int o0 = ot * 128, p0 = pt * 128;
  int tid = threadIdx.x;
  int lane = tid & 63, wave = tid >> 6;
  int ml = lane & 15, quad = lane >> 4;
  int wm = (wave & 1) * 64, wn = (wave >> 1) * 64;
  int a_row = tid >> 1, a_cs = (tid & 1) * 16;
  int b_p = tid & 127, b_cs = (tid >> 7) * 16;
  const u16* ab = attn + (size_t)b * CIN * NPIX + p0 + b_p;

  f32x4 acc[4][4];
#pragma unroll
  for (int i = 0; i < 4; ++i)
#pragma unroll
    for (int j = 0; j < 4; ++j) acc[i][j] = (f32x4){0.f, 0.f, 0.f, 0.f};

  for (int kc = 0; kc < CIN; kc += 32) {
    {
      const float* ap = wo + (size_t)(o0 + a_row) * CIN + kc + a_cs;
      u16 t[16];
#pragma unroll
      for (int i = 0; i < 16; ++i) t[i] = f2bf(ap[i]);
      uint4 v0 = make_uint4(pk(t[0], t[1]), pk(t[2], t[3]), pk(t[4], t[5]), pk(t[6], t[7]));
      uint4 v1 = make_uint4(pk(t[8], t[9]), pk(t[10], t[11]), pk(t[12], t[13]), pk(t[14], t[15]));
      *(uint4*)&As[a_row * LDK + a_cs] = v0;
      *(uint4*)&As[a_row * LDK + a_cs + 8] = v1;
    }
    {
      u16 t[16];
#pragma unroll
      for (int i = 0; i < 16; ++i) t[i] = ab[(size_t)(kc + b_cs + i) * NPIX];
      uint4 v0 = make_uint4(pk(t[0], t[1]), pk(t[2], t[3]), pk(t[4], t[5]), pk(t[6], t[7]));
      uint4 v1 = make_uint4(pk(t[8], t[9]), pk(t[10], t[11]), pk(t[12], t[13]), pk(t[14], t[15]));
      *(uint4*)&Bs[b_p * LDK + b_cs] = v0;
      *(uint4*)&Bs[b_p * LDK + b_cs + 8] = v1;
    }
    __syncthreads();
    bf16x8 af[4], bfr[4];
#pragma unroll
    for (int mt = 0; mt < 4; ++mt)
      af[mt] = *(const bf16x8*)&As[(wm + mt * 16 + ml) * LDK + quad * 8];
#pragma unroll
    for (int nt = 0; nt < 4; ++nt)
      bfr[nt] = *(const bf16x8*)&Bs[(wn + nt * 16 + ml) * LDK + quad * 8];
#pragma unroll
    for (int mt = 0; mt < 4; ++mt)
#pragma unroll
      for (int nt = 0; nt < 4; ++nt)
        acc[mt][nt] = __builtin_amdgcn_mfma_f32_16x16x32_bf16(af[mt], bfr[nt], acc[mt][nt], 0, 0, 0);
    __syncthreads();
  }
#pragma unroll
  for (int mt = 0; mt < 4; ++mt)
#pragma unroll
    for (int nt = 0; nt < 4; ++nt) {
      int o = o0 + wm + mt * 16 + quad * 4;
      int p = p0 + wn + nt * 16 + ml;
      size_t base = ((size_t)(b * CIN + o)) * NPIX + p;
#pragma unroll
      for (int r = 0; r < 4; ++r) {
        size_t gi = base + (size_t)r * NPIX;
        out[gi] = acc[mt][nt][r] + x[gi];
      }
    }
}

extern "C" void kernel_launch(void* const* d_in, const int* in_sizes, int n_in,
                              void* d_out, int out_size, void* d_ws, size_t ws_size,
                              hipStream_t stream) {
  const float* x = (const float*)d_in[0];
  const float* lnw = (const float*)d_in[1];
  const float* wp = (const float*)d_in[2];
  const float* wd = (const float*)d_in[3];
  const float* wo = (const float*)d_in[4];
  const float* alpha = (const float*)d_in[5];
  float* out = (float*)d_out;

  // ws layout (bytes):
  //   [0, 512K)        mu
  //   [512K, 1M)       rstd
  //   [1M, 1M+302M)    region1: qkv_pre (bf16, 302MB); after dconv it is dead and
  //                    re-used as: attn (bf16, 100.7MB) + partial (fp32, 37.7MB)
  //                    + scoreT (bf16, 0.4MB)
  //   [303,038,464, +302,514,176)  qkv_post (bf16, + 16 channel rows of slack for
  //                                the K-padded V reads of the last (b,h))
  // total = 605,552,640 B
  char* ws = (char*)d_ws;
  float* mu = (float*)ws;
  float* rstd = (float*)(ws + 524288);
  u16* qkv_pre = (u16*)(ws + 1048576);
  u16* attn = qkv_pre;
  float* partial = (float*)(ws + 1048576 + 100663296);
  u16* scoreT = (u16*)(ws + 1048576 + 100663296 + 37748736);
  u16* qkv_post = (u16*)(ws + 303038464);

  hipLaunchKernelGGL(k_stats, dim3(512), dim3(256), 0, stream, x, mu, rstd);
  hipLaunchKernelGGL(k_pconv, dim3(NB * 9 * 128), dim3(256), 0, stream, x, wp, lnw, mu, rstd, qkv_pre);
  hipLaunchKernelGGL(k_dconv, dim3(NB * C3 * 8), dim3(256), 0, stream, qkv_pre, wd, qkv_post);
  hipLaunchKernelGGL(k_score, dim3(64 * 64), dim3(64), 0, stream, qkv_post, partial);
  hipLaunchKernelGGL(k_softmax, dim3(64), dim3(256), 0, stream, partial, alpha, scoreT);
  hipLaunchKernelGGL(k_attnv, dim3(NB * 8 * 128), dim3(256), 0, stream, qkv_post, scoreT, attn);
  hipLaunchKernelGGL(k_out, dim3(NB * 3 * 128), dim3(256), 0, stream, attn, wo, x, out);
}

// Round 2
// 1043.064 us; speedup vs baseline: 1.7538x; 1.1729x over previous
//
#include <hip/hip_runtime.h>

typedef unsigned short u16;
typedef unsigned int u32;
typedef __bf16 bf16;
typedef bf16 bf16x8 __attribute__((ext_vector_type(8)));
typedef float f32x4 __attribute__((ext_vector_type(4)));

#define CIN 384
#define C3 1152
#define NPIX 16384
#define NB 8
#define DH 48
#define IMG 128
#define BK 32

__device__ __forceinline__ u16 f2bf(float f) {
  u32 u = __float_as_uint(f);
  u32 r = (u + 0x7fffu + ((u >> 16) & 1u)) >> 16;  // RNE
  return (u16)r;
}
__device__ __forceinline__ float bf2f(u16 a) { return __uint_as_float(((u32)a) << 16); }
__device__ __forceinline__ u32 pk(u16 a, u16 b) { return (u32)a | ((u32)b << 16); }

// ---------------- K-1: weights -> bf16 ----------------
__global__ __launch_bounds__(256) void k_wcvt(const float* __restrict__ wp,
                                              const float* __restrict__ wo,
                                              u16* __restrict__ wpb,
                                              u16* __restrict__ wob) {
  int i = blockIdx.x * 256 + threadIdx.x;
  if (i < C3 * CIN) wpb[i] = f2bf(wp[i]);
  if (i < CIN * CIN) wob[i] = f2bf(wo[i]);
}

// ---------------- K0: fused LN stats + normalize + transpose -> xn_t[b][p][c] bf16 ----------------
__global__ __launch_bounds__(256) void k_norm(const float* __restrict__ x,
                                              const float* __restrict__ lnw,
                                              u16* __restrict__ xnt) {
  int idx = blockIdx.x * 256 + threadIdx.x;   // B*N = 131072
  int b = idx >> 14, p = idx & (NPIX - 1);
  const float* xp = x + (size_t)b * CIN * NPIX + p;
  float s = 0.f, s2 = 0.f;
#pragma unroll 4
  for (int c = 0; c < CIN; ++c) {
    float v = xp[(size_t)c * NPIX];
    s += v; s2 += v * v;
  }
  float m = s * (1.f / CIN);
  float rs = rsqrtf(s2 * (1.f / CIN) - m * m + 1e-5f);
  u16* op = xnt + (size_t)idx * CIN;
  for (int c0 = 0; c0 < CIN; c0 += 16) {   // second pass: L2-resident re-reads
    u16 t[16];
#pragma unroll
    for (int i = 0; i < 16; ++i)
      t[i] = f2bf((xp[(size_t)(c0 + i) * NPIX] - m) * rs * lnw[c0 + i]);
    uint4 v0 = make_uint4(pk(t[0], t[1]), pk(t[2], t[3]), pk(t[4], t[5]), pk(t[6], t[7]));
    uint4 v1 = make_uint4(pk(t[8], t[9]), pk(t[10], t[11]), pk(t[12], t[13]), pk(t[14], t[15]));
    *(uint4*)&op[c0] = v0;
    *(uint4*)&op[c0 + 8] = v1;
  }
}

// ---------------- K1: pointwise conv GEMM (pure bf16, vector staging) ----------------
// qkv_pre[b][o][p] = sum_c Wb[o][c] * xn_t[b][p][c]
// LDS: [row][BK] with 16B-chunk XOR swizzle: chunk' = (chunk + (row>>1)) & 3
// -> both ds_write_b128 staging and ds_read_b128 frags land 2-way (free).
__global__ __launch_bounds__(256) void k_pconv(const u16* __restrict__ wpb,
                                               const u16* __restrict__ xnt,
                                               u16* __restrict__ qkv_pre) {
  __shared__ u16 As[128 * BK];
  __shared__ u16 Bs[128 * BK];
  int blk = blockIdx.x;
  int pt = blk & 127;
  int ot = (blk >> 7) % 9;
  int b = blk / (9 * 128);
  int o0 = ot * 128, p0 = pt * 128;
  int tid = threadIdx.x;
  int lane = tid & 63, wave = tid >> 6;
  int ml = lane & 15, quad = lane >> 4;
  int wm = (wave & 1) * 64, wn = (wave >> 1) * 64;
  int r0 = tid >> 2, k8 = tid & 3;           // 16B chunk (row, k-chunk)
  int sk = (k8 + (r0 >> 1)) & 3;             // swizzled slot (same for row r0 and r0+64)
  const u16* aG = wpb + (size_t)(o0 + r0) * CIN + k8 * 8;
  const u16* bG = xnt + ((size_t)((b << 14) + p0 + r0)) * CIN + k8 * 8;

  f32x4 acc[4][4];
#pragma unroll
  for (int i = 0; i < 4; ++i)
#pragma unroll
    for (int j = 0; j < 4; ++j) acc[i][j] = (f32x4){0.f, 0.f, 0.f, 0.f};

  for (int kc = 0; kc < CIN; kc += BK) {
    uint4 a0 = *(const uint4*)(aG + kc);
    uint4 a1 = *(const uint4*)(aG + (size_t)64 * CIN + kc);
    uint4 b0 = *(const uint4*)(bG + kc);
    uint4 b1 = *(const uint4*)(bG + (size_t)64 * CIN + kc);
    *(uint4*)&As[r0 * BK + sk * 8] = a0;
    *(uint4*)&As[(r0 + 64) * BK + sk * 8] = a1;
    *(uint4*)&Bs[r0 * BK + sk * 8] = b0;
    *(uint4*)&Bs[(r0 + 64) * BK + sk * 8] = b1;
    __syncthreads();
    bf16x8 af[4], bfr[4];
#pragma unroll
    for (int mt = 0; mt < 4; ++mt) {
      int rw = wm + mt * 16 + ml;
      af[mt] = *(const bf16x8*)&As[rw * BK + (((quad + (rw >> 1)) & 3) * 8)];
    }
#pragma unroll
    for (int nt = 0; nt < 4; ++nt) {
      int rw = wn + nt * 16 + ml;
      bfr[nt] = *(const bf16x8*)&Bs[rw * BK + (((quad + (rw >> 1)) & 3) * 8)];
    }
#pragma unroll
    for (int mt = 0; mt < 4; ++mt)
#pragma unroll
      for (int nt = 0; nt < 4; ++nt)
        acc[mt][nt] = __builtin_amdgcn_mfma_f32_16x16x32_bf16(af[mt], bfr[nt], acc[mt][nt], 0, 0, 0);
    __syncthreads();
  }
#pragma unroll
  for (int mt = 0; mt < 4; ++mt)
#pragma unroll
    for (int nt = 0; nt < 4; ++nt) {
      int o = o0 + wm + mt * 16 + quad * 4;
      int p = p0 + wn + nt * 16 + ml;
      size_t base = ((size_t)(b * C3 + o)) * NPIX + p;
#pragma unroll
      for (int r = 0; r < 4; ++r)
        qkv_pre[base + (size_t)r * NPIX] = f2bf(acc[mt][nt][r]);
    }
}

// ---------------- K2: depthwise 3x3 — 8x4 px/thread, loads hoisted ----------------
__global__ __launch_bounds__(256) void k_dconv(const u16* __restrict__ pre,
                                               const float* __restrict__ wd,
                                               u16* __restrict__ post) {
  int bidx = blockIdx.x;
  int cg = bidx >> 1;                 // b*C3 + ch   (2 blocks per channel image)
  int half = bidx & 1;
  int ch = cg % C3;
  int tid = threadIdx.x;
  int y0 = half * 64 + (tid >> 4) * 4;
  int x0 = (tid & 15) * 8;
  const u16* pb = pre + (size_t)cg * NPIX;
  const float* wc = wd + ch * 9;
  float w[9];
#pragma unroll
  for (int i = 0; i < 9; ++i) w[i] = wc[i];

  uint4 v[6];
  u16 eL[6], eR[6];
#pragma unroll
  for (int r = 0; r < 6; ++r) {
    int yy = y0 + r - 1;
    bool ok = ((unsigned)yy < (unsigned)IMG);
    const u16* row = pb + yy * IMG + x0;
    v[r] = ok ? *(const uint4*)row : make_uint4(0u, 0u, 0u, 0u);
    eL[r] = (ok && x0 > 0) ? row[-1] : (u16)0;
    eR[r] = (ok && x0 < IMG - 8) ? row[8] : (u16)0;
  }

  float acc[4][8];
#pragma unroll
  for (int j = 0; j < 4; ++j)
#pragma unroll
    for (int i = 0; i < 8; ++i) acc[j][i] = 0.f;

#pragma unroll
  for (int r = 0; r < 6; ++r) {
    float rr[10];
    const u16* pv = (const u16*)&v[r];
    rr[0] = bf2f(eL[r]);
    rr[9] = bf2f(eR[r]);
#pragma unroll
    for (int i = 0; i < 8; ++i) rr[i + 1] = bf2f(pv[i]);
#pragma unroll
    for (int j = 0; j < 4; ++j) {
      int ky = r - j;
      if (ky < 0 || ky > 2) continue;    // constant-folded (both loops unrolled)
      float w0 = w[ky * 3 + 0], w1 = w[ky * 3 + 1], w2 = w[ky * 3 + 2];
#pragma unroll
      for (int i = 0; i < 8; ++i)
        acc[j][i] += rr[i] * w0 + rr[i + 1] * w1 + rr[i + 2] * w2;
    }
  }
#pragma unroll
  for (int j = 0; j < 4; ++j) {
    u16 o[8];
#pragma unroll
    for (int i = 0; i < 8; ++i) o[i] = f2bf(acc[j][i]);
    uint4 ov = make_uint4(pk(o[0], o[1]), pk(o[2], o[3]), pk(o[4], o[5]), pk(o[6], o[7]));
    *(uint4*)(post + (size_t)cg * NPIX + (y0 + j) * IMG + x0) = ov;
  }
}

// ---------------- K3: Q^T K split-K partials ----------------
__global__ __launch_bounds__(64) void k_score(const u16* __restrict__ post,
                                              float* __restrict__ partial) {
  int blk = blockIdx.x;  // bh*64 + chunk
  int chunk = blk & 63, bh = blk >> 6;
  int b = bh >> 3, h = bh & 7;
  int lane = threadIdx.x;
  int ml = lane & 15, quad = lane >> 4;
  int n0 = chunk * 256;
  const u16* qp[3];
  const u16* kp[3];
#pragma unroll
  for (int t = 0; t < 3; ++t) {
    qp[t] = post + ((size_t)(b * C3 + h * DH + t * 16 + ml)) * NPIX + n0 + quad * 8;
    kp[t] = post + ((size_t)(b * C3 + CIN + h * DH + t * 16 + ml)) * NPIX + n0 + quad * 8;
  }
  f32x4 acc[3][3];
#pragma unroll
  for (int i = 0; i < 3; ++i)
#pragma unroll
    for (int j = 0; j < 3; ++j) acc[i][j] = (f32x4){0.f, 0.f, 0.f, 0.f};
  for (int ks = 0; ks < 256; ks += 32) {
    bf16x8 qf[3], kf[3];
#pragma unroll
    for (int t = 0; t < 3; ++t) {
      qf[t] = *(const bf16x8*)(qp[t] + ks);
      kf[t] = *(const bf16x8*)(kp[t] + ks);
    }
#pragma unroll
    for (int it = 0; it < 3; ++it)
#pragma unroll
      for (int jt = 0; jt < 3; ++jt)
        acc[it][jt] = __builtin_amdgcn_mfma_f32_16x16x32_bf16(qf[it], kf[jt], acc[it][jt], 0, 0, 0);
  }
  float* pp = partial + (size_t)blk * (DH * DH);
#pragma unroll
  for (int it = 0; it < 3; ++it)
#pragma unroll
    for (int jt = 0; jt < 3; ++jt)
#pragma unroll
      for (int r = 0; r < 4; ++r)
        pp[(it * 16 + quad * 4 + r) * DH + jt * 16 + ml] = acc[it][jt][r];
}

// ---------------- K4: reduce partials, softmax, emit score^T (K-padded) ----------------
__global__ __launch_bounds__(256) void k_softmax(const float* __restrict__ partial,
                                                 const float* __restrict__ alpha,
                                                 u16* __restrict__ scoreT) {
  __shared__ float sc[DH * DH];
  __shared__ float pr[DH * DH];
  int bh = blockIdx.x, tid = threadIdx.x;
  const float* pp = partial + (size_t)bh * 64 * (DH * DH);
  for (int e = tid; e < DH * DH; e += 256) {
    float s = 0.f;
    for (int c = 0; c < 64; ++c) s += pp[(size_t)c * (DH * DH) + e];
    sc[e] = s;
  }
  __syncthreads();
  float inv_a = 1.0f / alpha[0];
  if (tid < DH) {
    int i = tid;
    float mx = -1e30f;
    for (int j = 0; j < DH; ++j) mx = fmaxf(mx, sc[i * DH + j] * inv_a);
    float sum = 0.f;
    for (int j = 0; j < DH; ++j) {
      float e = __expf(sc[i * DH + j] * inv_a - mx);
      pr[i * DH + j] = e;
      sum += e;
    }
    float r = 1.f / sum;
    for (int j = 0; j < DH; ++j) pr[i * DH + j] *= r;
  }
  __syncthreads();
  u16* st = scoreT + (size_t)bh * DH * 64;
  for (int e = tid; e < DH * 64; e += 256) {
    int j = e >> 6, i = e & 63;
    st[e] = f2bf(i < DH ? pr[i * DH + j] : 0.f);  // zero-pad K to 64
  }
}

// ---------------- K5: attn_t[b][p][c] = sum_i score^T[j][i] * v[i][n] ----------------
#define VS_LD 72
__global__ __launch_bounds__(256) void k_attnv(const u16* __restrict__ post,
                                               const u16* __restrict__ scoreT,
                                               u16* __restrict__ attn_t) {
  __shared__ u16 Vs[128 * VS_LD];  // V^T tile: [n][i], i-contig
  int blk = blockIdx.x;
  int pt = blk & 127, h = (blk >> 7) & 7, b = blk >> 10;
  int p0 = pt * 128;
  int tid = threadIdx.x, lane = tid & 63, wave = tid >> 6;
  int ml = lane & 15, quad = lane >> 4;
  {  // stage V transposed: thread owns one n, 32 i's (clamped to valid channels)
    int n = tid & 127;
    int i0 = (tid >> 7) * 32;
    size_t vbase = ((size_t)(b * C3 + 2 * CIN + h * DH)) * NPIX + p0 + n;
    u16 t[32];
#pragma unroll
    for (int i = 0; i < 32; ++i) {
      int ic = i0 + i;
      int icc = ic < DH ? ic : (DH - 1);   // i>=DH multiplied by zero score
      t[i] = post[vbase + (size_t)icc * NPIX];
    }
#pragma unroll
    for (int q2 = 0; q2 < 4; ++q2) {
      uint4 v = make_uint4(pk(t[q2 * 8 + 0], t[q2 * 8 + 1]), pk(t[q2 * 8 + 2], t[q2 * 8 + 3]),
                           pk(t[q2 * 8 + 4], t[q2 * 8 + 5]), pk(t[q2 * 8 + 6], t[q2 * 8 + 7]));
      *(uint4*)&Vs[n * VS_LD + i0 + q2 * 8] = v;
    }
  }
  __syncthreads();
  const u16* sT = scoreT + (size_t)(b * 8 + h) * (DH * 64);
  int wn = wave * 32;
  f32x4 acc[3][2];
#pragma unroll
  for (int i = 0; i < 3; ++i)
#pragma unroll
    for (int j = 0; j < 2; ++j) acc[i][j] = (f32x4){0.f, 0.f, 0.f, 0.f};
#pragma unroll
  for (int ks = 0; ks < 2; ++ks) {
    bf16x8 a3[3], b2[2];
#pragma unroll
    for (int mt = 0; mt < 3; ++mt)
      a3[mt] = *(const bf16x8*)&sT[(mt * 16 + ml) * 64 + ks * 32 + quad * 8];
#pragma unroll
    for (int nt = 0; nt < 2; ++nt)
      b2[nt] = *(const bf16x8*)&Vs[(wn + nt * 16 + ml) * VS_LD + ks * 32 + quad * 8];
#pragma unroll
    for (int mt = 0; mt < 3; ++mt)
#pragma unroll
      for (int nt = 0; nt < 2; ++nt)
        acc[mt][nt] = __builtin_amdgcn_mfma_f32_16x16x32_bf16(a3[mt], b2[nt], acc[mt][nt], 0, 0, 0);
  }
#pragma unroll
  for (int mt = 0; mt < 3; ++mt)
#pragma unroll
    for (int nt = 0; nt < 2; ++nt) {
      int j0 = mt * 16 + quad * 4;
      int n = wn + nt * 16 + ml;
      u16 o4[4];
#pragma unroll
      for (int r = 0; r < 4; ++r) o4[r] = f2bf(acc[mt][nt][r]);
      uint2 ov = make_uint2(pk(o4[0], o4[1]), pk(o4[2], o4[3]));
      *(uint2*)&attn_t[((size_t)((b << 14) + p0 + n)) * CIN + h * DH + j0] = ov;
    }
}

// ---------------- K6: output GEMM + residual (bf16 vector staging) ----------------
__global__ __launch_bounds__(256) void k_out(const u16* __restrict__ wob,
                                             const u16* __restrict__ attn_t,
                                             const float* __restrict__ x,
                                             float* __restrict__ out) {
  __shared__ u16 As[128 * BK];
  __shared__ u16 Bs[128 * BK];
  int blk = blockIdx.x;
  int pt = blk & 127;
  int ot = (blk >> 7) % 3;
  int b = blk / (3 * 128);
  int o0 = ot * 128, p0 = pt * 128;
  int tid = threadIdx.x;
  int lane = tid & 63, wave = tid >> 6;
  int ml = lane & 15, quad = lane >> 4;
  int wm = (wave & 1) * 64, wn = (wave >> 1) * 64;
  int r0 = tid >> 2, k8 = tid & 3;
  int sk = (k8 + (r0 >> 1)) & 3;
  const u16* aG = wob + (size_t)(o0 + r0) * CIN + k8 * 8;
  const u16* bG = attn_t + ((size_t)((b << 14) + p0 + r0)) * CIN + k8 * 8;

  f32x4 acc[4][4];
#pragma unroll
  for (int i = 0; i < 4; ++i)
#pragma unroll
    for (int j = 0; j < 4; ++j) acc[i][j] = (f32x4){0.f, 0.f, 0.f, 0.f};

  for (int kc = 0; kc < CIN; kc += BK) {
    uint4 a0 = *(const uint4*)(aG + kc);
    uint4 a1 = *(const uint4*)(aG + (size_t)64 * CIN + kc);
    uint4 b0 = *(const uint4*)(bG + kc);
    uint4 b1 = *(const uint4*)(bG + (size_t)64 * CIN + kc);
    *(uint4*)&As[r0 * BK + sk * 8] = a0;
    *(uint4*)&As[(r0 + 64) * BK + sk * 8] = a1;
    *(uint4*)&Bs[r0 * BK + sk * 8] = b0;
    *(uint4*)&Bs[(r0 + 64) * BK + sk * 8] = b1;
    __syncthreads();
    bf16x8 af[4], bfr[4];
#pragma unroll
    for (int mt = 0; mt < 4; ++mt) {
      int rw = wm + mt * 16 + ml;
      af[mt] = *(const bf16x8*)&As[rw * BK + (((quad + (rw >> 1)) & 3) * 8)];
    }
#pragma unroll
    for (int nt = 0; nt < 4; ++nt) {
      int rw = wn + nt * 16 + ml;
      bfr[nt] = *(const bf16x8*)&Bs[rw * BK + (((quad + (rw >> 1)) & 3) * 8)];
    }
#pragma unroll
    for (int mt = 0; mt < 4; ++mt)
#pragma unroll
      for (int nt = 0; nt < 4; ++nt)
        acc[mt][nt] = __builtin_amdgcn_mfma_f32_16x16x32_bf16(af[mt], bfr[nt], acc[mt][nt], 0, 0, 0);
    __syncthreads();
  }
#pragma unroll
  for (int mt = 0; mt < 4; ++mt)
#pragma unroll
    for (int nt = 0; nt < 4; ++nt) {
      int o = o0 + wm + mt * 16 + quad * 4;
      int p = p0 + wn + nt * 16 + ml;
      size_t base = ((size_t)(b * CIN + o)) * NPIX + p;
#pragma unroll
      for (int r = 0; r < 4; ++r) {
        size_t gi = base + (size_t)r * NPIX;
        out[gi] = acc[mt][nt][r] + x[gi];
      }
    }
}

extern "C" void kernel_launch(void* const* d_in, const int* in_sizes, int n_in,
                              void* d_out, int out_size, void* d_ws, size_t ws_size,
                              hipStream_t stream) {
  const float* x = (const float*)d_in[0];
  const float* lnw = (const float*)d_in[1];
  const float* wp = (const float*)d_in[2];
  const float* wd = (const float*)d_in[3];
  const float* wo = (const float*)d_in[4];
  const float* alpha = (const float*)d_in[5];
  float* out = (float*)d_out;

  // ws layout (bytes), total 605,159,424:
  //   [0, 884736)                  wpb  (bf16 1152x384)
  //   [884736, 1179648)            wob  (bf16 384x384)
  //   [1179648, +301,989,888)      qkv_pre (bf16); dead after dconv, re-used as:
  //        attn_t  at +0          (100,663,296)
  //        partial at +100663296  (37,748,736)
  //        scoreT  at +138412032.. (393,216)
  //   [303,169,536, +301,989,888)  qkv_post (bf16, no slack needed: V reads clamped)
  // xn_t (bf16 [b][p][c], 100.7MB) lives in d_out (dead until k_out writes it).
  char* ws = (char*)d_ws;
  u16* wpb = (u16*)ws;
  u16* wob = (u16*)(ws + 884736);
  u16* qkv_pre = (u16*)(ws + 1179648);
  u16* attn_t = qkv_pre;
  float* partial = (float*)(ws + 1179648 + 100663296);
  u16* scoreT = (u16*)(ws + 1179648 + 100663296 + 37748736);
  u16* qkv_post = (u16*)(ws + 303169536);
  u16* xnt = (u16*)d_out;

  hipLaunchKernelGGL(k_wcvt, dim3(1728), dim3(256), 0, stream, wp, wo, wpb, wob);
  hipLaunchKernelGGL(k_norm, dim3(512), dim3(256), 0, stream, x, lnw, xnt);
  hipLaunchKernelGGL(k_pconv, dim3(NB * 9 * 128), dim3(256), 0, stream, wpb, xnt, qkv_pre);
  hipLaunchKernelGGL(k_dconv, dim3(NB * C3 * 2), dim3(256), 0, stream, qkv_pre, wd, qkv_post);
  hipLaunchKernelGGL(k_score, dim3(64 * 64), dim3(64), 0, stream, qkv_post, partial);
  hipLaunchKernelGGL(k_softmax, dim3(64), dim3(256), 0, stream, partial, alpha, scoreT);
  hipLaunchKernelGGL(k_attnv, dim3(NB * 8 * 128), dim3(256), 0, stream, qkv_post, scoreT, attn_t);
  hipLaunchKernelGGL(k_out, dim3(NB * 3 * 128), dim3(256), 0, stream, wob, attn_t, x, out);
}

// Round 3
// 1006.259 us; speedup vs baseline: 1.8180x; 1.0366x over previous
//
#include <hip/hip_runtime.h>

typedef unsigned short u16;
typedef unsigned int u32;
typedef __bf16 bf16;
typedef bf16 bf16x8 __attribute__((ext_vector_type(8)));
typedef float f32x4 __attribute__((ext_vector_type(4)));

#define CIN 384
#define C3 1152
#define NPIX 16384
#define NB 8
#define DH 48
#define IMG 128
#define BK 32

__device__ __forceinline__ u16 f2bf(float f) {
  u32 u = __float_as_uint(f);
  u32 r = (u + 0x7fffu + ((u >> 16) & 1u)) >> 16;  // RNE
  return (u16)r;
}
__device__ __forceinline__ float bf2f(u16 a) { return __uint_as_float(((u32)a) << 16); }
__device__ __forceinline__ u32 pk(u16 a, u16 b) { return (u32)a | ((u32)b << 16); }

// async global->LDS, 16B per lane; LDS dest = wave-uniform base + lane*16
__device__ __forceinline__ void gload16(const u16* g, u16* l) {
  __builtin_amdgcn_global_load_lds((const __attribute__((address_space(1))) void*)g,
                                   (__attribute__((address_space(3))) void*)l, 16, 0, 0);
}

// ---------------- K-1: weights -> bf16 ----------------
__global__ __launch_bounds__(256) void k_wcvt(const float* __restrict__ wp,
                                              const float* __restrict__ wo,
                                              u16* __restrict__ wpb,
                                              u16* __restrict__ wob) {
  int i = blockIdx.x * 256 + threadIdx.x;
  if (i < C3 * CIN) wpb[i] = f2bf(wp[i]);
  if (i < CIN * CIN) wob[i] = f2bf(wo[i]);
}

// ---------------- K0: fused LN stats + normalize + transpose -> xn_t[b][p][c] bf16 ----------------
__global__ __launch_bounds__(256) void k_norm(const float* __restrict__ x,
                                              const float* __restrict__ lnw,
                                              u16* __restrict__ xnt) {
  int idx = blockIdx.x * 256 + threadIdx.x;   // B*N = 131072
  int b = idx >> 14, p = idx & (NPIX - 1);
  const float* xp = x + (size_t)b * CIN * NPIX + p;
  float s = 0.f, s2 = 0.f;
#pragma unroll 4
  for (int c = 0; c < CIN; ++c) {
    float v = xp[(size_t)c * NPIX];
    s += v; s2 += v * v;
  }
  float m = s * (1.f / CIN);
  float rs = rsqrtf(s2 * (1.f / CIN) - m * m + 1e-5f);
  u16* op = xnt + (size_t)idx * CIN;
  for (int c0 = 0; c0 < CIN; c0 += 16) {   // second pass: L2-resident re-reads
    u16 t[16];
#pragma unroll
    for (int i = 0; i < 16; ++i)
      t[i] = f2bf((xp[(size_t)(c0 + i) * NPIX] - m) * rs * lnw[c0 + i]);
    uint4 v0 = make_uint4(pk(t[0], t[1]), pk(t[2], t[3]), pk(t[4], t[5]), pk(t[6], t[7]));
    uint4 v1 = make_uint4(pk(t[8], t[9]), pk(t[10], t[11]), pk(t[12], t[13]), pk(t[14], t[15]));
    *(uint4*)&op[c0] = v0;
    *(uint4*)&op[c0 + 8] = v1;
  }
}

// ---------------- K1: pointwise conv GEMM (global_load_lds staging) ----------------
// qkv_pre[b][o][p] = sum_c Wb[o][c] * xn_t[b][p][c]
// LDS: [row][BK], 16B chunk at slot (chunk + (row>>1))&3 (swizzle -> conflict-free
// frag reads). gload_lds writes linearly (lane l -> row l>>2, slot l&3 of a 16-row
// segment), so the SOURCE chunk is pre-swizzled: ck = ((l&3) - ((l>>3)&3)) & 3.
__global__ __launch_bounds__(256) void k_pconv(const u16* __restrict__ wpb,
                                               const u16* __restrict__ xnt,
                                               u16* __restrict__ qkv_pre) {
  __shared__ u16 As[128 * BK];
  __shared__ u16 Bs[128 * BK];
  int blk = blockIdx.x;
  int pt = blk & 127;
  int ot = (blk >> 7) % 9;
  int b = blk / (9 * 128);
  int o0 = ot * 128, p0 = pt * 128;
  int tid = threadIdx.x;
  int lane = tid & 63, wave = tid >> 6;
  int ml = lane & 15, quad = lane >> 4;
  int wm = (wave & 1) * 64, wn = (wave >> 1) * 64;

  int lr = lane >> 2;                              // row within 16-row segment
  int ck = ((lane & 3) - ((lane >> 3) & 3)) & 3;   // pre-swizzled source chunk
  const u16* srcA0 = wpb + (size_t)(o0 + 32 * wave + lr) * CIN + ck * 8;
  const u16* srcA1 = srcA0 + (size_t)16 * CIN;
  const u16* srcB0 = xnt + ((size_t)((b << 14) + p0 + 32 * wave + lr)) * CIN + ck * 8;
  const u16* srcB1 = srcB0 + (size_t)16 * CIN;
  u16* dA0 = &As[(32 * wave) * BK];
  u16* dA1 = &As[(32 * wave + 16) * BK];
  u16* dB0 = &Bs[(32 * wave) * BK];
  u16* dB1 = &Bs[(32 * wave + 16) * BK];

  f32x4 acc[4][4];
#pragma unroll
  for (int i = 0; i < 4; ++i)
#pragma unroll
    for (int j = 0; j < 4; ++j) acc[i][j] = (f32x4){0.f, 0.f, 0.f, 0.f};

  for (int kc = 0; kc < CIN; kc += BK) {
    gload16(srcA0 + kc, dA0);
    gload16(srcA1 + kc, dA1);
    gload16(srcB0 + kc, dB0);
    gload16(srcB1 + kc, dB1);
    __syncthreads();
    bf16x8 af[4], bfr[4];
#pragma unroll
    for (int mt = 0; mt < 4; ++mt) {
      int rw = wm + mt * 16 + ml;
      af[mt] = *(const bf16x8*)&As[rw * BK + (((quad + (rw >> 1)) & 3) * 8)];
    }
#pragma unroll
    for (int nt = 0; nt < 4; ++nt) {
      int rw = wn + nt * 16 + ml;
      bfr[nt] = *(const bf16x8*)&Bs[rw * BK + (((quad + (rw >> 1)) & 3) * 8)];
    }
#pragma unroll
    for (int mt = 0; mt < 4; ++mt)
#pragma unroll
      for (int nt = 0; nt < 4; ++nt)
        acc[mt][nt] = __builtin_amdgcn_mfma_f32_16x16x32_bf16(af[mt], bfr[nt], acc[mt][nt], 0, 0, 0);
    __syncthreads();
  }
#pragma unroll
  for (int mt = 0; mt < 4; ++mt)
#pragma unroll
    for (int nt = 0; nt < 4; ++nt) {
      int o = o0 + wm + mt * 16 + quad * 4;
      int p = p0 + wn + nt * 16 + ml;
      size_t base = ((size_t)(b * C3 + o)) * NPIX + p;
#pragma unroll
      for (int r = 0; r < 4; ++r)
        qkv_pre[base + (size_t)r * NPIX] = f2bf(acc[mt][nt][r]);
    }
}

// ---------------- K2: depthwise 3x3 — 8x4 px/thread, loads hoisted ----------------
__global__ __launch_bounds__(256) void k_dconv(const u16* __restrict__ pre,
                                               const float* __restrict__ wd,
                                               u16* __restrict__ post) {
  int bidx = blockIdx.x;
  int cg = bidx >> 1;                 // b*C3 + ch   (2 blocks per channel image)
  int half = bidx & 1;
  int ch = cg % C3;
  int tid = threadIdx.x;
  int y0 = half * 64 + (tid >> 4) * 4;
  int x0 = (tid & 15) * 8;
  const u16* pb = pre + (size_t)cg * NPIX;
  const float* wc = wd + ch * 9;
  float w[9];
#pragma unroll
  for (int i = 0; i < 9; ++i) w[i] = wc[i];

  uint4 v[6];
  u16 eL[6], eR[6];
#pragma unroll
  for (int r = 0; r < 6; ++r) {
    int yy = y0 + r - 1;
    bool ok = ((unsigned)yy < (unsigned)IMG);
    const u16* row = pb + yy * IMG + x0;
    v[r] = ok ? *(const uint4*)row : make_uint4(0u, 0u, 0u, 0u);
    eL[r] = (ok && x0 > 0) ? row[-1] : (u16)0;
    eR[r] = (ok && x0 < IMG - 8) ? row[8] : (u16)0;
  }

  float acc[4][8];
#pragma unroll
  for (int j = 0; j < 4; ++j)
#pragma unroll
    for (int i = 0; i < 8; ++i) acc[j][i] = 0.f;

#pragma unroll
  for (int r = 0; r < 6; ++r) {
    float rr[10];
    const u16* pv = (const u16*)&v[r];
    rr[0] = bf2f(eL[r]);
    rr[9] = bf2f(eR[r]);
#pragma unroll
    for (int i = 0; i < 8; ++i) rr[i + 1] = bf2f(pv[i]);
#pragma unroll
    for (int j = 0; j < 4; ++j) {
      int ky = r - j;
      if (ky < 0 || ky > 2) continue;    // constant-folded (both loops unrolled)
      float w0 = w[ky * 3 + 0], w1 = w[ky * 3 + 1], w2 = w[ky * 3 + 2];
#pragma unroll
      for (int i = 0; i < 8; ++i)
        acc[j][i] += rr[i] * w0 + rr[i + 1] * w1 + rr[i + 2] * w2;
    }
  }
#pragma unroll
  for (int j = 0; j < 4; ++j) {
    u16 o[8];
#pragma unroll
    for (int i = 0; i < 8; ++i) o[i] = f2bf(acc[j][i]);
    uint4 ov = make_uint4(pk(o[0], o[1]), pk(o[2], o[3]), pk(o[4], o[5]), pk(o[6], o[7]));
    *(uint4*)(post + (size_t)cg * NPIX + (y0 + j) * IMG + x0) = ov;
  }
}

// ---------------- K3: Q^T K split-K partials ----------------
__global__ __launch_bounds__(64) void k_score(const u16* __restrict__ post,
                                              float* __restrict__ partial) {
  int blk = blockIdx.x;  // bh*64 + chunk
  int chunk = blk & 63, bh = blk >> 6;
  int b = bh >> 3, h = bh & 7;
  int lane = threadIdx.x;
  int ml = lane & 15, quad = lane >> 4;
  int n0 = chunk * 256;
  const u16* qp[3];
  const u16* kp[3];
#pragma unroll
  for (int t = 0; t < 3; ++t) {
    qp[t] = post + ((size_t)(b * C3 + h * DH + t * 16 + ml)) * NPIX + n0 + quad * 8;
    kp[t] = post + ((size_t)(b * C3 + CIN + h * DH + t * 16 + ml)) * NPIX + n0 + quad * 8;
  }
  f32x4 acc[3][3];
#pragma unroll
  for (int i = 0; i < 3; ++i)
#pragma unroll
    for (int j = 0; j < 3; ++j) acc[i][j] = (f32x4){0.f, 0.f, 0.f, 0.f};
  for (int ks = 0; ks < 256; ks += 32) {
    bf16x8 qf[3], kf[3];
#pragma unroll
    for (int t = 0; t < 3; ++t) {
      qf[t] = *(const bf16x8*)(qp[t] + ks);
      kf[t] = *(const bf16x8*)(kp[t] + ks);
    }
#pragma unroll
    for (int it = 0; it < 3; ++it)
#pragma unroll
      for (int jt = 0; jt < 3; ++jt)
        acc[it][jt] = __builtin_amdgcn_mfma_f32_16x16x32_bf16(qf[it], kf[jt], acc[it][jt], 0, 0, 0);
  }
  float* pp = partial + (size_t)blk * (DH * DH);
#pragma unroll
  for (int it = 0; it < 3; ++it)
#pragma unroll
    for (int jt = 0; jt < 3; ++jt)
#pragma unroll
      for (int r = 0; r < 4; ++r)
        pp[(it * 16 + quad * 4 + r) * DH + jt * 16 + ml] = acc[it][jt][r];
}

// ---------------- K4: reduce partials, softmax, emit score^T (K-padded) ----------------
__global__ __launch_bounds__(256) void k_softmax(const float* __restrict__ partial,
                                                 const float* __restrict__ alpha,
                                                 u16* __restrict__ scoreT) {
  __shared__ float sc[DH * DH];
  __shared__ float pr[DH * DH];
  int bh = blockIdx.x, tid = threadIdx.x;
  const float* pp = partial + (size_t)bh * 64 * (DH * DH);
  for (int e = tid; e < DH * DH; e += 256) {
    float s = 0.f;
    for (int c = 0; c < 64; ++c) s += pp[(size_t)c * (DH * DH) + e];
    sc[e] = s;
  }
  __syncthreads();
  float inv_a = 1.0f / alpha[0];
  if (tid < DH) {
    int i = tid;
    float mx = -1e30f;
    for (int j = 0; j < DH; ++j) mx = fmaxf(mx, sc[i * DH + j] * inv_a);
    float sum = 0.f;
    for (int j = 0; j < DH; ++j) {
      float e = __expf(sc[i * DH + j] * inv_a - mx);
      pr[i * DH + j] = e;
      sum += e;
    }
    float r = 1.f / sum;
    for (int j = 0; j < DH; ++j) pr[i * DH + j] *= r;
  }
  __syncthreads();
  u16* st = scoreT + (size_t)bh * DH * 64;
  for (int e = tid; e < DH * 64; e += 256) {
    int j = e >> 6, i = e & 63;
    st[e] = f2bf(i < DH ? pr[i * DH + j] : 0.f);  // zero-pad K to 64
  }
}

// ---------------- K5: attn_t[b][p][c] = sum_i score^T[j][i] * v[i][n] ----------------
#define VS_LD 72
__global__ __launch_bounds__(256) void k_attnv(const u16* __restrict__ post,
                                               const u16* __restrict__ scoreT,
                                               u16* __restrict__ attn_t) {
  __shared__ u16 Vs[128 * VS_LD];  // V^T tile: [n][i], i-contig
  int blk = blockIdx.x;
  int pt = blk & 127, h = (blk >> 7) & 7, b = blk >> 10;
  int p0 = pt * 128;
  int tid = threadIdx.x, lane = tid & 63, wave = tid >> 6;
  int ml = lane & 15, quad = lane >> 4;
  {  // stage V transposed: thread owns one n, 32 i's (clamped to valid channels)
    int n = tid & 127;
    int i0 = (tid >> 7) * 32;
    size_t vbase = ((size_t)(b * C3 + 2 * CIN + h * DH)) * NPIX + p0 + n;
    u16 t[32];
#pragma unroll
    for (int i = 0; i < 32; ++i) {
      int ic = i0 + i;
      int icc = ic < DH ? ic : (DH - 1);   // i>=DH multiplied by zero score
      t[i] = post[vbase + (size_t)icc * NPIX];
    }
#pragma unroll
    for (int q2 = 0; q2 < 4; ++q2) {
      uint4 v = make_uint4(pk(t[q2 * 8 + 0], t[q2 * 8 + 1]), pk(t[q2 * 8 + 2], t[q2 * 8 + 3]),
                           pk(t[q2 * 8 + 4], t[q2 * 8 + 5]), pk(t[q2 * 8 + 6], t[q2 * 8 + 7]));
      *(uint4*)&Vs[n * VS_LD + i0 + q2 * 8] = v;
    }
  }
  __syncthreads();
  const u16* sT = scoreT + (size_t)(b * 8 + h) * (DH * 64);
  int wn = wave * 32;
  f32x4 acc[3][2];
#pragma unroll
  for (int i = 0; i < 3; ++i)
#pragma unroll
    for (int j = 0; j < 2; ++j) acc[i][j] = (f32x4){0.f, 0.f, 0.f, 0.f};
#pragma unroll
  for (int ks = 0; ks < 2; ++ks) {
    bf16x8 a3[3], b2[2];
#pragma unroll
    for (int mt = 0; mt < 3; ++mt)
      a3[mt] = *(const bf16x8*)&sT[(mt * 16 + ml) * 64 + ks * 32 + quad * 8];
#pragma unroll
    for (int nt = 0; nt < 2; ++nt)
      b2[nt] = *(const bf16x8*)&Vs[(wn + nt * 16 + ml) * VS_LD + ks * 32 + quad * 8];
#pragma unroll
    for (int mt = 0; mt < 3; ++mt)
#pragma unroll
      for (int nt = 0; nt < 2; ++nt)
        acc[mt][nt] = __builtin_amdgcn_mfma_f32_16x16x32_bf16(a3[mt], b2[nt], acc[mt][nt], 0, 0, 0);
  }
#pragma unroll
  for (int mt = 0; mt < 3; ++mt)
#pragma unroll
    for (int nt = 0; nt < 2; ++nt) {
      int j0 = mt * 16 + quad * 4;
      int n = wn + nt * 16 + ml;
      u16 o4[4];
#pragma unroll
      for (int r = 0; r < 4; ++r) o4[r] = f2bf(acc[mt][nt][r]);
      uint2 ov = make_uint2(pk(o4[0], o4[1]), pk(o4[2], o4[3]));
      *(uint2*)&attn_t[((size_t)((b << 14) + p0 + n)) * CIN + h * DH + j0] = ov;
    }
}

// ---------------- K6: output GEMM + residual (global_load_lds staging) ----------------
__global__ __launch_bounds__(256) void k_out(const u16* __restrict__ wob,
                                             const u16* __restrict__ attn_t,
                                             const float* __restrict__ x,
                                             float* __restrict__ out) {
  __shared__ u16 As[128 * BK];
  __shared__ u16 Bs[128 * BK];
  int blk = blockIdx.x;
  int pt = blk & 127;
  int ot = (blk >> 7) % 3;
  int b = blk / (3 * 128);
  int o0 = ot * 128, p0 = pt * 128;
  int tid = threadIdx.x;
  int lane = tid & 63, wave = tid >> 6;
  int ml = lane & 15, quad = lane >> 4;
  int wm = (wave & 1) * 64, wn = (wave >> 1) * 64;

  int lr = lane >> 2;
  int ck = ((lane & 3) - ((lane >> 3) & 3)) & 3;
  const u16* srcA0 = wob + (size_t)(o0 + 32 * wave + lr) * CIN + ck * 8;
  const u16* srcA1 = srcA0 + (size_t)16 * CIN;
  const u16* srcB0 = attn_t + ((size_t)((b << 14) + p0 + 32 * wave + lr)) * CIN + ck * 8;
  const u16* srcB1 = srcB0 + (size_t)16 * CIN;
  u16* dA0 = &As[(32 * wave) * BK];
  u16* dA1 = &As[(32 * wave + 16) * BK];
  u16* dB0 = &Bs[(32 * wave) * BK];
  u16* dB1 = &Bs[(32 * wave + 16) * BK];

  f32x4 acc[4][4];
#pragma unroll
  for (int i = 0; i < 4; ++i)
#pragma unroll
    for (int j = 0; j < 4; ++j) acc[i][j] = (f32x4){0.f, 0.f, 0.f, 0.f};

  for (int kc = 0; kc < CIN; kc += BK) {
    gload16(srcA0 + kc, dA0);
    gload16(srcA1 + kc, dA1);
    gload16(srcB0 + kc, dB0);
    gload16(srcB1 + kc, dB1);
    __syncthreads();
    bf16x8 af[4], bfr[4];
#pragma unroll
    for (int mt = 0; mt < 4; ++mt) {
      int rw = wm + mt * 16 + ml;
      af[mt] = *(const bf16x8*)&As[rw * BK + (((quad + (rw >> 1)) & 3) * 8)];
    }
#pragma unroll
    for (int nt = 0; nt < 4; ++nt) {
      int rw = wn + nt * 16 + ml;
      bfr[nt] = *(const bf16x8*)&Bs[rw * BK + (((quad + (rw >> 1)) & 3) * 8)];
    }
#pragma unroll
    for (int mt = 0; mt < 4; ++mt)
#pragma unroll
      for (int nt = 0; nt < 4; ++nt)
        acc[mt][nt] = __builtin_amdgcn_mfma_f32_16x16x32_bf16(af[mt], bfr[nt], acc[mt][nt], 0, 0, 0);
    __syncthreads();
  }
#pragma unroll
  for (int mt = 0; mt < 4; ++mt)
#pragma unroll
    for (int nt = 0; nt < 4; ++nt) {
      int o = o0 + wm + mt * 16 + quad * 4;
      int p = p0 + wn + nt * 16 + ml;
      size_t base = ((size_t)(b * CIN + o)) * NPIX + p;
#pragma unroll
      for (int r = 0; r < 4; ++r) {
        size_t gi = base + (size_t)r * NPIX;
        out[gi] = acc[mt][nt][r] + x[gi];
      }
    }
}

extern "C" void kernel_launch(void* const* d_in, const int* in_sizes, int n_in,
                              void* d_out, int out_size, void* d_ws, size_t ws_size,
                              hipStream_t stream) {
  const float* x = (const float*)d_in[0];
  const float* lnw = (const float*)d_in[1];
  const float* wp = (const float*)d_in[2];
  const float* wd = (const float*)d_in[3];
  const float* wo = (const float*)d_in[4];
  const float* alpha = (const float*)d_in[5];
  float* out = (float*)d_out;

  // ws layout (bytes), total 605,159,424:
  //   [0, 884736)                  wpb  (bf16 1152x384)
  //   [884736, 1179648)            wob  (bf16 384x384)
  //   [1179648, +301,989,888)      qkv_pre (bf16); dead after dconv, re-used as:
  //        attn_t  at +0          (100,663,296)
  //        partial at +100663296  (37,748,736)
  //        scoreT  at +138412032.. (393,216)
  //   [303,169,536, +301,989,888)  qkv_post (bf16)
  // xn_t (bf16 [b][p][c], 100.7MB) lives in d_out (dead until k_out writes it).
  char* ws = (char*)d_ws;
  u16* wpb = (u16*)ws;
  u16* wob = (u16*)(ws + 884736);
  u16* qkv_pre = (u16*)(ws + 1179648);
  u16* attn_t = qkv_pre;
  float* partial = (float*)(ws + 1179648 + 100663296);
  u16* scoreT = (u16*)(ws + 1179648 + 100663296 + 37748736);
  u16* qkv_post = (u16*)(ws + 303169536);
  u16* xnt = (u16*)d_out;

  hipLaunchKernelGGL(k_wcvt, dim3(1728), dim3(256), 0, stream, wp, wo, wpb, wob);
  hipLaunchKernelGGL(k_norm, dim3(512), dim3(256), 0, stream, x, lnw, xnt);
  hipLaunchKernelGGL(k_pconv, dim3(NB * 9 * 128), dim3(256), 0, stream, wpb, xnt, qkv_pre);
  hipLaunchKernelGGL(k_dconv, dim3(NB * C3 * 2), dim3(256), 0, stream, qkv_pre, wd, qkv_post);
  hipLaunchKernelGGL(k_score, dim3(64 * 64), dim3(64), 0, stream, qkv_post, partial);
  hipLaunchKernelGGL(k_softmax, dim3(64), dim3(256), 0, stream, partial, alpha, scoreT);
  hipLaunchKernelGGL(k_attnv, dim3(NB * 8 * 128), dim3(256), 0, stream, qkv_post, scoreT, attn_t);
  hipLaunchKernelGGL(k_out, dim3(NB * 3 * 128), dim3(256), 0, stream, wob, attn_t, x, out);
}